// Round 12
// baseline (144.658 us; speedup 1.0000x reference)
//
#include <hip/hip_runtime.h>
#include <hip/hip_bf16.h>

typedef __attribute__((ext_vector_type(8))) short bf16x8;
typedef __attribute__((ext_vector_type(4))) float f32x4;

#define K_DIM 256
#define N_DIM 512
#define BM 32
#define M_DIM 65536
#define TPB 4                        // x-tiles per block
#define GRID (M_DIM / BM / TPB)      // 512 blocks = 2 per CU

// round-to-nearest-even fp32 -> bf16 bits
__device__ __forceinline__ unsigned short f2bf(float f) {
    unsigned int u = __float_as_uint(f);
    unsigned int r = (u + 0x7fffu + ((u >> 16) & 1u)) >> 16;
    return (unsigned short)r;
}

// barrier that does NOT drain global stores/loads: LDS-visibility only.
__device__ __forceinline__ void barrier_lds() {
    asm volatile("s_waitcnt lgkmcnt(0)" ::: "memory");
    __builtin_amdgcn_s_barrier();
}

// Kernel 1: clusters fp32 -> bf16 ARRANGED per-(wc,ks,n,lane) fragment order
// (wave wc owns 64 cluster cols) + fp32 row norms.
// arranged[wc][ks][n][L][ko] = clusters[wc*64 + n*16 + (L&15)][ks*32 + (L>>4)*8 + ko]
__global__ __launch_bounds__(256) void prep_clusters(
        const float* __restrict__ clusters,
        unsigned short* __restrict__ cba,
        float* __restrict__ csq) {
    const int row = blockIdx.x;   // 512 cluster rows
    const int t = threadIdx.x;    // 256 = K_DIM
    const float v = clusters[row * K_DIM + t];
    const int wc = row >> 6, n = (row >> 4) & 3, r = row & 15;
    const int ks = t >> 5, kh = (t >> 3) & 3, ko = t & 7;
    cba[(size_t)wc * 16384 + ks * 2048 + n * 512 + (kh * 16 + r) * 8 + ko] = f2bf(v);
    float s = v * v;
    #pragma unroll
    for (int m = 1; m < 64; m <<= 1) s += __shfl_xor(s, m);
    __shared__ float red[4];
    if ((t & 63) == 0) red[t >> 6] = s;
    __syncthreads();
    if (t == 0) csq[row] = red[0] + red[1] + red[2] + red[3];
}

// Kernel 2: R7 structure (clusters in registers, 8 waves x 64 cols, x through
// double-buffered swizzled LDS, one lgkm-only barrier per tile) but with
// TWO blocks per CU (GRID=512, TPB=4, VGPR cap 128): independent blocks
// de-phase so one block's memory phases overlap the other's compute phases.
__global__ __launch_bounds__(512, 4) void cluster_q(
        const float* __restrict__ x,
        const unsigned short* __restrict__ cba,
        const float* __restrict__ csq,
        float* __restrict__ out) {
    __shared__ __align__(16) unsigned short xa[2][BM * K_DIM]; // 2 x 16 KB, XOR-swizzled
    __shared__ float xsq[2][BM];
    __shared__ __align__(16) float csql[N_DIM];
    __shared__ float rsum[2][8][BM];

    const int t = threadIdx.x;
    const int lane = t & 63;
    const int wc = t >> 6;        // wave 0..7 = 64-col cluster group

    // ---- prologue: this wave's cluster slice -> registers, permanently ----
    const unsigned short* gsrc = cba + (size_t)wc * 16384;
    bf16x8 breg[8][4];
    #pragma unroll
    for (int ks = 0; ks < 8; ++ks)
        #pragma unroll
        for (int n = 0; n < 4; ++n)
            breg[ks][n] = *reinterpret_cast<const bf16x8*>(
                              gsrc + ks * 2048 + n * 512 + lane * 8);

    csql[t] = csq[t];   // t in [0,512)

    const size_t base = (size_t)blockIdx.x * (TPB * BM);

    float4 xr0, xr1, xr2, xr3;
    // load tile 0 (wave wc owns rows wc, wc+8, wc+16, wc+24)
    {
        const float4* xp = reinterpret_cast<const float4*>(x + (base + wc) * K_DIM);
        xr0 = xp[lane]; xr1 = xp[512 + lane]; xr2 = xp[1024 + lane]; xr3 = xp[1536 + lane];
    }
    // stage tile 0 into buffer 0
    {
        const float4 vv[4] = {xr0, xr1, xr2, xr3};
        #pragma unroll
        for (int p = 0; p < 4; ++p) {
            const int row = wc + p * 8;
            const float4 v = vv[p];
            float s = v.x * v.x + v.y * v.y + v.z * v.z + v.w * v.w;
            #pragma unroll
            for (int m = 1; m < 64; m <<= 1) s += __shfl_xor(s, m);
            if (lane == 0) xsq[0][row] = s;
            const ushort4 pk = make_ushort4(f2bf(v.x), f2bf(v.y), f2bf(v.z), f2bf(v.w));
            const int swz = (lane * 8) ^ ((row & 7) << 4);
            *reinterpret_cast<ushort4*>(
                reinterpret_cast<char*>(xa[0]) + row * 512 + swz) = pk;
        }
    }
    // issue tile 1's loads (fly across the barrier; staged at iteration 0)
    {
        const float4* xp = reinterpret_cast<const float4*>(x + (base + BM + wc) * K_DIM);
        xr0 = xp[lane]; xr1 = xp[512 + lane]; xr2 = xp[1024 + lane]; xr3 = xp[1536 + lane];
    }
    barrier_lds();

    for (int it = 0; it < TPB; ++it) {
        const int cur = it & 1, nxt = cur ^ 1;
        const size_t rowbase = base + (size_t)it * BM;

        // ---- stage tile it+1 into buffer nxt ----
        if (it + 1 < TPB) {
            const float4 vv[4] = {xr0, xr1, xr2, xr3};
            #pragma unroll
            for (int p = 0; p < 4; ++p) {
                const int row = wc + p * 8;
                const float4 v = vv[p];
                float s = v.x * v.x + v.y * v.y + v.z * v.z + v.w * v.w;
                #pragma unroll
                for (int m = 1; m < 64; m <<= 1) s += __shfl_xor(s, m);
                if (lane == 0) xsq[nxt][row] = s;
                const ushort4 pk = make_ushort4(f2bf(v.x), f2bf(v.y), f2bf(v.z), f2bf(v.w));
                const int swz = (lane * 8) ^ ((row & 7) << 4);
                *reinterpret_cast<ushort4*>(
                    reinterpret_cast<char*>(xa[nxt]) + row * 512 + swz) = pk;
            }
        }
        // ---- issue tile it+2's loads ----
        if (it + 2 < TPB) {
            const float4* xp = reinterpret_cast<const float4*>(
                                   x + (rowbase + 2 * BM + wc) * K_DIM);
            xr0 = xp[lane]; xr1 = xp[512 + lane]; xr2 = xp[1024 + lane]; xr3 = xp[1536 + lane];
        }
        __builtin_amdgcn_sched_barrier(0);   // pin staging+load issue above K-loop

        // ---- K-loop: A = clusters (registers), B = x (LDS) ----
        f32x4 acc[2][4];
        #pragma unroll
        for (int m = 0; m < 2; ++m)
            #pragma unroll
            for (int n = 0; n < 4; ++n)
                acc[m][n] = (f32x4){0.f, 0.f, 0.f, 0.f};

        const char* xab = reinterpret_cast<const char*>(xa[cur]);
        #pragma unroll
        for (int ks = 0; ks < 8; ++ks) {
            const int r0 = (lane & 15);
            const int r1 = 16 + (lane & 15);
            const int c0 = (ks * 64 + (lane >> 4) * 16) ^ ((r0 & 7) << 4);
            const int c1 = (ks * 64 + (lane >> 4) * 16) ^ ((r1 & 7) << 4);
            const bf16x8 xm0 = *reinterpret_cast<const bf16x8*>(xab + r0 * 512 + c0);
            const bf16x8 xm1 = *reinterpret_cast<const bf16x8*>(xab + r1 * 512 + c1);
            #pragma unroll
            for (int n = 0; n < 4; ++n) {
                acc[0][n] = __builtin_amdgcn_mfma_f32_16x16x32_bf16(breg[ks][n], xm0, acc[0][n], 0, 0, 0);
                acc[1][n] = __builtin_amdgcn_mfma_f32_16x16x32_bf16(breg[ks][n], xm1, acc[1][n], 0, 0, 0);
            }
        }

        // ---- epilogue: D[ccol][xrow]; lane: xrow = m*16+(lane&15),
        //      ccol = wc*64 + n*16 + (lane>>4)*4 + j (4 consecutive) ----
        const float4* csql4 = reinterpret_cast<const float4*>(csql);
        float part[2] = {0.f, 0.f};
        #pragma unroll
        for (int m = 0; m < 2; ++m) {
            const float xs1 = 1.f + xsq[cur][m * 16 + (lane & 15)];
            #pragma unroll
            for (int n = 0; n < 4; ++n) {
                const float4 cs = csql4[wc * 16 + n * 4 + (lane >> 4)];
                f32x4 q;
                q[0] = __builtin_amdgcn_rcpf(fmaf(-2.f, acc[m][n][0], xs1 + cs.x));
                q[1] = __builtin_amdgcn_rcpf(fmaf(-2.f, acc[m][n][1], xs1 + cs.y));
                q[2] = __builtin_amdgcn_rcpf(fmaf(-2.f, acc[m][n][2], xs1 + cs.z));
                q[3] = __builtin_amdgcn_rcpf(fmaf(-2.f, acc[m][n][3], xs1 + cs.w));
                acc[m][n] = q;
                part[m] += (q[0] + q[1]) + (q[2] + q[3]);
            }
        }
        // reduce across the 4 lane-groups (same xrow), write per-wave partial
        #pragma unroll
        for (int m = 0; m < 2; ++m) {
            float s = part[m];
            s += __shfl_xor(s, 16);
            s += __shfl_xor(s, 32);
            if (lane < 16) rsum[cur][wc][m * 16 + lane] = s;
        }
        // the ONLY barrier per tile (lgkm-only; global stores stay in flight)
        barrier_lds();

        // normalize + float4 stores
        #pragma unroll
        for (int m = 0; m < 2; ++m) {
            const int b = m * 16 + (lane & 15);
            const float inv = __builtin_amdgcn_rcpf(
                ((rsum[cur][0][b] + rsum[cur][1][b]) + (rsum[cur][2][b] + rsum[cur][3][b])) +
                ((rsum[cur][4][b] + rsum[cur][5][b]) + (rsum[cur][6][b] + rsum[cur][7][b])));
            float* orow = out + (rowbase + b) * N_DIM + wc * 64 + (lane >> 4) * 4;
            #pragma unroll
            for (int n = 0; n < 4; ++n) {
                const f32x4 v = acc[m][n];
                float4 st = make_float4(v[0] * inv, v[1] * inv, v[2] * inv, v[3] * inv);
                *reinterpret_cast<float4*>(orow + n * 16) = st;
            }
        }
    }
}

extern "C" void kernel_launch(void* const* d_in, const int* in_sizes, int n_in,
                              void* d_out, int out_size, void* d_ws, size_t ws_size,
                              hipStream_t stream) {
    const float* x        = (const float*)d_in[0];
    const float* clusters = (const float*)d_in[1];
    float* out = (float*)d_out;
    unsigned short* cba = (unsigned short*)d_ws;                      // 256 KB arranged
    float* csq = (float*)((char*)d_ws + (size_t)N_DIM * K_DIM * 2);   // + 2 KB
    prep_clusters<<<N_DIM, K_DIM, 0, stream>>>(clusters, cba, csq);
    cluster_q<<<GRID, 512, 0, stream>>>(x, cba, csq, out);
}

// Round 14
// 55.919 us; speedup vs baseline: 2.5869x; 2.5869x over previous
//
#include <hip/hip_runtime.h>
#include <hip/hip_bf16.h>

typedef __attribute__((ext_vector_type(8))) short bf16x8;
typedef __attribute__((ext_vector_type(4))) float f32x4;

#define K_DIM 256
#define N_DIM 512
#define BM 32
#define M_DIM 65536
#define TPB 8                        // x-tiles per block
#define GRID (M_DIM / BM / TPB)      // 256 blocks = 1 per CU

// round-to-nearest-even fp32 -> bf16 bits (used in cold prep kernel)
__device__ __forceinline__ unsigned short f2bf(float f) {
    unsigned int u = __float_as_uint(f);
    unsigned int r = (u + 0x7fffu + ((u >> 16) & 1u)) >> 16;
    return (unsigned short)r;
}

// pack 4 fp32 -> 4 bf16 (RNE) via v_cvt_pk_bf16_f32; bit-identical to f2bf
__device__ __forceinline__ uint2 pack_bf16x4(float4 v) {
    __hip_bfloat162 a = __float22bfloat162_rn(make_float2(v.x, v.y));
    __hip_bfloat162 b = __float22bfloat162_rn(make_float2(v.z, v.w));
    uint2 r;
    r.x = *reinterpret_cast<unsigned int*>(&a);
    r.y = *reinterpret_cast<unsigned int*>(&b);
    return r;
}

// barrier that does NOT drain global stores/loads: LDS-visibility only.
__device__ __forceinline__ void barrier_lds() {
    asm volatile("s_waitcnt lgkmcnt(0)" ::: "memory");
    __builtin_amdgcn_s_barrier();
}

// Kernel 1: clusters fp32 -> bf16 ARRANGED per-(wc,ks,n,lane) fragment order
// (wave wc owns 64 cluster cols) + fp32 row norms.
// arranged[wc][ks][n][L][ko] = clusters[wc*64 + n*16 + (L&15)][ks*32 + (L>>4)*8 + ko]
__global__ __launch_bounds__(256) void prep_clusters(
        const float* __restrict__ clusters,
        unsigned short* __restrict__ cba,
        float* __restrict__ csq) {
    const int row = blockIdx.x;   // 512 cluster rows
    const int t = threadIdx.x;    // 256 = K_DIM
    const float v = clusters[row * K_DIM + t];
    const int wc = row >> 6, n = (row >> 4) & 3, r = row & 15;
    const int ks = t >> 5, kh = (t >> 3) & 3, ko = t & 7;
    cba[(size_t)wc * 16384 + ks * 2048 + n * 512 + (kh * 16 + r) * 8 + ko] = f2bf(v);
    float s = v * v;
    #pragma unroll
    for (int m = 1; m < 64; m <<= 1) s += __shfl_xor(s, m);
    __shared__ float red[4];
    if ((t & 63) == 0) red[t >> 6] = s;
    __syncthreads();
    if (t == 0) csq[row] = red[0] + red[1] + red[2] + red[3];
}

// Kernel 2: R7 structure (clusters in registers, 8 waves x 64 cols, x through
// double-buffered swizzled LDS, one lgkm-only barrier per tile) +
// nontemporal output stores (write stream bypasses L2/L3 -> x stays cached) +
// v_cvt_pk_bf16_f32 staging (half the conversion VALU).
__global__ __launch_bounds__(512, 2) void cluster_q(
        const float* __restrict__ x,
        const unsigned short* __restrict__ cba,
        const float* __restrict__ csq,
        float* __restrict__ out) {
    __shared__ __align__(16) unsigned short xa[2][BM * K_DIM]; // 2 x 16 KB, XOR-swizzled
    __shared__ float xsq[2][BM];
    __shared__ __align__(16) float csql[N_DIM];
    __shared__ float rsum[2][8][BM];

    const int t = threadIdx.x;
    const int lane = t & 63;
    const int wc = t >> 6;        // wave 0..7 = 64-col cluster group

    // ---- prologue: this wave's cluster slice -> registers, permanently ----
    const unsigned short* gsrc = cba + (size_t)wc * 16384;
    bf16x8 breg[8][4];
    #pragma unroll
    for (int ks = 0; ks < 8; ++ks)
        #pragma unroll
        for (int n = 0; n < 4; ++n)
            breg[ks][n] = *reinterpret_cast<const bf16x8*>(
                              gsrc + ks * 2048 + n * 512 + lane * 8);

    csql[t] = csq[t];   // t in [0,512)

    const size_t base = (size_t)blockIdx.x * (TPB * BM);

    float4 xr0, xr1, xr2, xr3;
    // load tile 0 (wave wc owns rows wc, wc+8, wc+16, wc+24)
    {
        const float4* xp = reinterpret_cast<const float4*>(x + (base + wc) * K_DIM);
        xr0 = xp[lane]; xr1 = xp[512 + lane]; xr2 = xp[1024 + lane]; xr3 = xp[1536 + lane];
    }
    // stage tile 0 into buffer 0
    {
        const float4 vv[4] = {xr0, xr1, xr2, xr3};
        #pragma unroll
        for (int p = 0; p < 4; ++p) {
            const int row = wc + p * 8;
            const float4 v = vv[p];
            float s = v.x * v.x + v.y * v.y + v.z * v.z + v.w * v.w;
            #pragma unroll
            for (int m = 1; m < 64; m <<= 1) s += __shfl_xor(s, m);
            if (lane == 0) xsq[0][row] = s;
            const uint2 pk = pack_bf16x4(v);
            const int swz = (lane * 8) ^ ((row & 7) << 4);
            *reinterpret_cast<uint2*>(
                reinterpret_cast<char*>(xa[0]) + row * 512 + swz) = pk;
        }
    }
    // issue tile 1's loads (fly across the barrier; staged at iteration 0)
    {
        const float4* xp = reinterpret_cast<const float4*>(x + (base + BM + wc) * K_DIM);
        xr0 = xp[lane]; xr1 = xp[512 + lane]; xr2 = xp[1024 + lane]; xr3 = xp[1536 + lane];
    }
    barrier_lds();

    for (int it = 0; it < TPB; ++it) {
        const int cur = it & 1, nxt = cur ^ 1;
        const size_t rowbase = base + (size_t)it * BM;

        // ---- stage tile it+1 into buffer nxt ----
        if (it + 1 < TPB) {
            const float4 vv[4] = {xr0, xr1, xr2, xr3};
            #pragma unroll
            for (int p = 0; p < 4; ++p) {
                const int row = wc + p * 8;
                const float4 v = vv[p];
                float s = v.x * v.x + v.y * v.y + v.z * v.z + v.w * v.w;
                #pragma unroll
                for (int m = 1; m < 64; m <<= 1) s += __shfl_xor(s, m);
                if (lane == 0) xsq[nxt][row] = s;
                const uint2 pk = pack_bf16x4(v);
                const int swz = (lane * 8) ^ ((row & 7) << 4);
                *reinterpret_cast<uint2*>(
                    reinterpret_cast<char*>(xa[nxt]) + row * 512 + swz) = pk;
            }
        }
        // ---- issue tile it+2's loads ----
        if (it + 2 < TPB) {
            const float4* xp = reinterpret_cast<const float4*>(
                                   x + (rowbase + 2 * BM + wc) * K_DIM);
            xr0 = xp[lane]; xr1 = xp[512 + lane]; xr2 = xp[1024 + lane]; xr3 = xp[1536 + lane];
        }
        __builtin_amdgcn_sched_barrier(0);   // pin staging+load issue above K-loop

        // ---- K-loop: A = clusters (registers), B = x (LDS) ----
        f32x4 acc[2][4];
        #pragma unroll
        for (int m = 0; m < 2; ++m)
            #pragma unroll
            for (int n = 0; n < 4; ++n)
                acc[m][n] = (f32x4){0.f, 0.f, 0.f, 0.f};

        const char* xab = reinterpret_cast<const char*>(xa[cur]);
        #pragma unroll
        for (int ks = 0; ks < 8; ++ks) {
            const int r0 = (lane & 15);
            const int r1 = 16 + (lane & 15);
            const int c0 = (ks * 64 + (lane >> 4) * 16) ^ ((r0 & 7) << 4);
            const int c1 = (ks * 64 + (lane >> 4) * 16) ^ ((r1 & 7) << 4);
            const bf16x8 xm0 = *reinterpret_cast<const bf16x8*>(xab + r0 * 512 + c0);
            const bf16x8 xm1 = *reinterpret_cast<const bf16x8*>(xab + r1 * 512 + c1);
            #pragma unroll
            for (int n = 0; n < 4; ++n) {
                acc[0][n] = __builtin_amdgcn_mfma_f32_16x16x32_bf16(breg[ks][n], xm0, acc[0][n], 0, 0, 0);
                acc[1][n] = __builtin_amdgcn_mfma_f32_16x16x32_bf16(breg[ks][n], xm1, acc[1][n], 0, 0, 0);
            }
        }

        // ---- epilogue: D[ccol][xrow]; lane: xrow = m*16+(lane&15),
        //      ccol = wc*64 + n*16 + (lane>>4)*4 + j (4 consecutive) ----
        const float4* csql4 = reinterpret_cast<const float4*>(csql);
        float part[2] = {0.f, 0.f};
        #pragma unroll
        for (int m = 0; m < 2; ++m) {
            const float xs1 = 1.f + xsq[cur][m * 16 + (lane & 15)];
            #pragma unroll
            for (int n = 0; n < 4; ++n) {
                const float4 cs = csql4[wc * 16 + n * 4 + (lane >> 4)];
                f32x4 q;
                q[0] = __builtin_amdgcn_rcpf(fmaf(-2.f, acc[m][n][0], xs1 + cs.x));
                q[1] = __builtin_amdgcn_rcpf(fmaf(-2.f, acc[m][n][1], xs1 + cs.y));
                q[2] = __builtin_amdgcn_rcpf(fmaf(-2.f, acc[m][n][2], xs1 + cs.z));
                q[3] = __builtin_amdgcn_rcpf(fmaf(-2.f, acc[m][n][3], xs1 + cs.w));
                acc[m][n] = q;
                part[m] += (q[0] + q[1]) + (q[2] + q[3]);
            }
        }
        // reduce across the 4 lane-groups (same xrow), write per-wave partial
        #pragma unroll
        for (int m = 0; m < 2; ++m) {
            float s = part[m];
            s += __shfl_xor(s, 16);
            s += __shfl_xor(s, 32);
            if (lane < 16) rsum[cur][wc][m * 16 + lane] = s;
        }
        // the ONLY barrier per tile (lgkm-only; global stores stay in flight)
        barrier_lds();

        // normalize + nontemporal f32x4 stores (bypass L2/L3)
        #pragma unroll
        for (int m = 0; m < 2; ++m) {
            const int b = m * 16 + (lane & 15);
            const float inv = __builtin_amdgcn_rcpf(
                ((rsum[cur][0][b] + rsum[cur][1][b]) + (rsum[cur][2][b] + rsum[cur][3][b])) +
                ((rsum[cur][4][b] + rsum[cur][5][b]) + (rsum[cur][6][b] + rsum[cur][7][b])));
            float* orow = out + (rowbase + b) * N_DIM + wc * 64 + (lane >> 4) * 4;
            #pragma unroll
            for (int n = 0; n < 4; ++n) {
                const f32x4 v = acc[m][n];
                f32x4 st;
                st[0] = v[0] * inv; st[1] = v[1] * inv;
                st[2] = v[2] * inv; st[3] = v[3] * inv;
                __builtin_nontemporal_store(st, reinterpret_cast<f32x4*>(orow + n * 16));
            }
        }
    }
}

extern "C" void kernel_launch(void* const* d_in, const int* in_sizes, int n_in,
                              void* d_out, int out_size, void* d_ws, size_t ws_size,
                              hipStream_t stream) {
    const float* x        = (const float*)d_in[0];
    const float* clusters = (const float*)d_in[1];
    float* out = (float*)d_out;
    unsigned short* cba = (unsigned short*)d_ws;                      // 256 KB arranged
    float* csq = (float*)((char*)d_ws + (size_t)N_DIM * K_DIM * 2);   // + 2 KB
    prep_clusters<<<N_DIM, K_DIM, 0, stream>>>(clusters, cba, csq);
    cluster_q<<<GRID, 512, 0, stream>>>(x, cba, csq, out);
}

// Round 15
// 50.597 us; speedup vs baseline: 2.8590x; 1.1052x over previous
//
#include <hip/hip_runtime.h>
#include <hip/hip_bf16.h>

typedef __attribute__((ext_vector_type(8))) short bf16x8;
typedef __attribute__((ext_vector_type(4))) float f32x4;

#define K_DIM 256
#define N_DIM 512
#define BM 32
#define M_DIM 65536
#define TPB 8                        // x-tiles per block
#define GRID (M_DIM / BM / TPB)      // 256 blocks = 1 per CU

// round-to-nearest-even fp32 -> bf16 bits (used in cold prep kernel)
__device__ __forceinline__ unsigned short f2bf(float f) {
    unsigned int u = __float_as_uint(f);
    unsigned int r = (u + 0x7fffu + ((u >> 16) & 1u)) >> 16;
    return (unsigned short)r;
}

// pack 4 fp32 -> 4 bf16 (RNE) via v_cvt_pk_bf16_f32; bit-identical to f2bf
__device__ __forceinline__ uint2 pack_bf16x4(float4 v) {
    __hip_bfloat162 a = __float22bfloat162_rn(make_float2(v.x, v.y));
    __hip_bfloat162 b = __float22bfloat162_rn(make_float2(v.z, v.w));
    uint2 r;
    r.x = *reinterpret_cast<unsigned int*>(&a);
    r.y = *reinterpret_cast<unsigned int*>(&b);
    return r;
}

// barrier that does NOT drain global stores/loads: LDS-visibility only.
__device__ __forceinline__ void barrier_lds() {
    asm volatile("s_waitcnt lgkmcnt(0)" ::: "memory");
    __builtin_amdgcn_s_barrier();
}

// Kernel 1: clusters fp32 -> bf16 ARRANGED per-(wc,ks,n,lane) fragment order
// (wave wc owns 64 cluster cols) + fp32 row norms.
// arranged[wc][ks][n][L][ko] = clusters[wc*64 + n*16 + (L&15)][ks*32 + (L>>4)*8 + ko]
__global__ __launch_bounds__(256) void prep_clusters(
        const float* __restrict__ clusters,
        unsigned short* __restrict__ cba,
        float* __restrict__ csq) {
    const int row = blockIdx.x;   // 512 cluster rows
    const int t = threadIdx.x;    // 256 = K_DIM
    const float v = clusters[row * K_DIM + t];
    const int wc = row >> 6, n = (row >> 4) & 3, r = row & 15;
    const int ks = t >> 5, kh = (t >> 3) & 3, ko = t & 7;
    cba[(size_t)wc * 16384 + ks * 2048 + n * 512 + (kh * 16 + r) * 8 + ko] = f2bf(v);
    float s = v * v;
    #pragma unroll
    for (int m = 1; m < 64; m <<= 1) s += __shfl_xor(s, m);
    __shared__ float red[4];
    if ((t & 63) == 0) red[t >> 6] = s;
    __syncthreads();
    if (t == 0) csq[row] = red[0] + red[1] + red[2] + red[3];
}

// Kernel 2: R7 structure — clusters permanently in registers (8 waves x 64
// cols, breg 128 VGPR/wave), x streamed through double-buffered XOR-swizzled
// LDS, ONE lgkm-only barrier per tile (global stores drain asynchronously
// through L2), cached float4 stores, cvt_pk bf16 staging.
__global__ __launch_bounds__(512, 2) void cluster_q(
        const float* __restrict__ x,
        const unsigned short* __restrict__ cba,
        const float* __restrict__ csq,
        float* __restrict__ out) {
    __shared__ __align__(16) unsigned short xa[2][BM * K_DIM]; // 2 x 16 KB, XOR-swizzled
    __shared__ float xsq[2][BM];
    __shared__ __align__(16) float csql[N_DIM];
    __shared__ float rsum[2][8][BM];

    const int t = threadIdx.x;
    const int lane = t & 63;
    const int wc = t >> 6;        // wave 0..7 = 64-col cluster group

    // ---- prologue: this wave's cluster slice -> registers, permanently ----
    const unsigned short* gsrc = cba + (size_t)wc * 16384;
    bf16x8 breg[8][4];
    #pragma unroll
    for (int ks = 0; ks < 8; ++ks)
        #pragma unroll
        for (int n = 0; n < 4; ++n)
            breg[ks][n] = *reinterpret_cast<const bf16x8*>(
                              gsrc + ks * 2048 + n * 512 + lane * 8);

    csql[t] = csq[t];   // t in [0,512)

    const size_t base = (size_t)blockIdx.x * (TPB * BM);

    float4 xr0, xr1, xr2, xr3;
    // load tile 0 (wave wc owns rows wc, wc+8, wc+16, wc+24)
    {
        const float4* xp = reinterpret_cast<const float4*>(x + (base + wc) * K_DIM);
        xr0 = xp[lane]; xr1 = xp[512 + lane]; xr2 = xp[1024 + lane]; xr3 = xp[1536 + lane];
    }
    // stage tile 0 into buffer 0
    {
        const float4 vv[4] = {xr0, xr1, xr2, xr3};
        #pragma unroll
        for (int p = 0; p < 4; ++p) {
            const int row = wc + p * 8;
            const float4 v = vv[p];
            float s = v.x * v.x + v.y * v.y + v.z * v.z + v.w * v.w;
            #pragma unroll
            for (int m = 1; m < 64; m <<= 1) s += __shfl_xor(s, m);
            if (lane == 0) xsq[0][row] = s;
            const uint2 pk = pack_bf16x4(v);
            const int swz = (lane * 8) ^ ((row & 7) << 4);
            *reinterpret_cast<uint2*>(
                reinterpret_cast<char*>(xa[0]) + row * 512 + swz) = pk;
        }
    }
    // issue tile 1's loads (fly across the barrier; staged at iteration 0)
    {
        const float4* xp = reinterpret_cast<const float4*>(x + (base + BM + wc) * K_DIM);
        xr0 = xp[lane]; xr1 = xp[512 + lane]; xr2 = xp[1024 + lane]; xr3 = xp[1536 + lane];
    }
    barrier_lds();

    for (int it = 0; it < TPB; ++it) {
        const int cur = it & 1, nxt = cur ^ 1;
        const size_t rowbase = base + (size_t)it * BM;

        // ---- stage tile it+1 into buffer nxt ----
        if (it + 1 < TPB) {
            const float4 vv[4] = {xr0, xr1, xr2, xr3};
            #pragma unroll
            for (int p = 0; p < 4; ++p) {
                const int row = wc + p * 8;
                const float4 v = vv[p];
                float s = v.x * v.x + v.y * v.y + v.z * v.z + v.w * v.w;
                #pragma unroll
                for (int m = 1; m < 64; m <<= 1) s += __shfl_xor(s, m);
                if (lane == 0) xsq[nxt][row] = s;
                const uint2 pk = pack_bf16x4(v);
                const int swz = (lane * 8) ^ ((row & 7) << 4);
                *reinterpret_cast<uint2*>(
                    reinterpret_cast<char*>(xa[nxt]) + row * 512 + swz) = pk;
            }
        }
        // ---- issue tile it+2's loads ----
        if (it + 2 < TPB) {
            const float4* xp = reinterpret_cast<const float4*>(
                                   x + (rowbase + 2 * BM + wc) * K_DIM);
            xr0 = xp[lane]; xr1 = xp[512 + lane]; xr2 = xp[1024 + lane]; xr3 = xp[1536 + lane];
        }
        __builtin_amdgcn_sched_barrier(0);   // pin staging+load issue above K-loop

        // ---- K-loop: A = clusters (registers), B = x (LDS) ----
        f32x4 acc[2][4];
        #pragma unroll
        for (int m = 0; m < 2; ++m)
            #pragma unroll
            for (int n = 0; n < 4; ++n)
                acc[m][n] = (f32x4){0.f, 0.f, 0.f, 0.f};

        const char* xab = reinterpret_cast<const char*>(xa[cur]);
        #pragma unroll
        for (int ks = 0; ks < 8; ++ks) {
            const int r0 = (lane & 15);
            const int r1 = 16 + (lane & 15);
            const int c0 = (ks * 64 + (lane >> 4) * 16) ^ ((r0 & 7) << 4);
            const int c1 = (ks * 64 + (lane >> 4) * 16) ^ ((r1 & 7) << 4);
            const bf16x8 xm0 = *reinterpret_cast<const bf16x8*>(xab + r0 * 512 + c0);
            const bf16x8 xm1 = *reinterpret_cast<const bf16x8*>(xab + r1 * 512 + c1);
            #pragma unroll
            for (int n = 0; n < 4; ++n) {
                acc[0][n] = __builtin_amdgcn_mfma_f32_16x16x32_bf16(breg[ks][n], xm0, acc[0][n], 0, 0, 0);
                acc[1][n] = __builtin_amdgcn_mfma_f32_16x16x32_bf16(breg[ks][n], xm1, acc[1][n], 0, 0, 0);
            }
        }

        // ---- epilogue: D[ccol][xrow]; lane: xrow = m*16+(lane&15),
        //      ccol = wc*64 + n*16 + (lane>>4)*4 + j (4 consecutive) ----
        const float4* csql4 = reinterpret_cast<const float4*>(csql);
        float part[2] = {0.f, 0.f};
        #pragma unroll
        for (int m = 0; m < 2; ++m) {
            const float xs1 = 1.f + xsq[cur][m * 16 + (lane & 15)];
            #pragma unroll
            for (int n = 0; n < 4; ++n) {
                const float4 cs = csql4[wc * 16 + n * 4 + (lane >> 4)];
                f32x4 q;
                q[0] = __builtin_amdgcn_rcpf(fmaf(-2.f, acc[m][n][0], xs1 + cs.x));
                q[1] = __builtin_amdgcn_rcpf(fmaf(-2.f, acc[m][n][1], xs1 + cs.y));
                q[2] = __builtin_amdgcn_rcpf(fmaf(-2.f, acc[m][n][2], xs1 + cs.z));
                q[3] = __builtin_amdgcn_rcpf(fmaf(-2.f, acc[m][n][3], xs1 + cs.w));
                acc[m][n] = q;
                part[m] += (q[0] + q[1]) + (q[2] + q[3]);
            }
        }
        // reduce across the 4 lane-groups (same xrow), write per-wave partial
        #pragma unroll
        for (int m = 0; m < 2; ++m) {
            float s = part[m];
            s += __shfl_xor(s, 16);
            s += __shfl_xor(s, 32);
            if (lane < 16) rsum[cur][wc][m * 16 + lane] = s;
        }
        // the ONLY barrier per tile (lgkm-only; global stores stay in flight)
        barrier_lds();

        // normalize + cached float4 stores (L2 absorbs; drains async)
        #pragma unroll
        for (int m = 0; m < 2; ++m) {
            const int b = m * 16 + (lane & 15);
            const float inv = __builtin_amdgcn_rcpf(
                ((rsum[cur][0][b] + rsum[cur][1][b]) + (rsum[cur][2][b] + rsum[cur][3][b])) +
                ((rsum[cur][4][b] + rsum[cur][5][b]) + (rsum[cur][6][b] + rsum[cur][7][b])));
            float* orow = out + (rowbase + b) * N_DIM + wc * 64 + (lane >> 4) * 4;
            #pragma unroll
            for (int n = 0; n < 4; ++n) {
                const f32x4 v = acc[m][n];
                float4 st = make_float4(v[0] * inv, v[1] * inv, v[2] * inv, v[3] * inv);
                *reinterpret_cast<float4*>(orow + n * 16) = st;
            }
        }
    }
}

extern "C" void kernel_launch(void* const* d_in, const int* in_sizes, int n_in,
                              void* d_out, int out_size, void* d_ws, size_t ws_size,
                              hipStream_t stream) {
    const float* x        = (const float*)d_in[0];
    const float* clusters = (const float*)d_in[1];
    float* out = (float*)d_out;
    unsigned short* cba = (unsigned short*)d_ws;                      // 256 KB arranged
    float* csq = (float*)((char*)d_ws + (size_t)N_DIM * K_DIM * 2);   // + 2 KB
    prep_clusters<<<N_DIM, K_DIM, 0, stream>>>(clusters, cba, csq);
    cluster_q<<<GRID, 512, 0, stream>>>(x, cba, csq, out);
}